// Round 8
// baseline (603.359 us; speedup 1.0000x reference)
//
#include <hip/hip_runtime.h>
#include <math.h>

#define NROWS  65536   // 16*64*64 rows
#define D      64
#define K      1024
#define KSPLIT 16
#define KPER   (K / KSPLIT)   // 64 codes per block -> 16 KB slice (K$-sized)
#define ROWS2  512            // rows per block (2 per thread)
#define BETA   0.25f

// ---------------------------------------------------------------- enorm ----
__global__ __launch_bounds__(256) void vq_enorm(const float* __restrict__ emb,
                                                float* __restrict__ enorm) {
    int k = blockIdx.x * 256 + threadIdx.x;
    if (k >= K) return;
    const float4* e4 = (const float4*)(emb + (size_t)k * D);
    float s = 0.f;
    #pragma unroll
    for (int i = 0; i < 16; ++i) {
        float4 e = e4[i];
        s += e.x * e.x + e.y * e.y + e.z * e.z + e.w * e.w;
    }
    enorm[k] = s;
}

// ----------------------------------------------------------------- main ----
// R5/R7 bracketed the binder: s_load path is K$-miss-bound at high TLP (R5)
// and latency-bound at low TLP (R7); both ~160us. Fix = REUSE: KSPLIT=16
// makes each block's e-slice 16 KB (scalar-cache-sized), and kq-MAJOR block
// mapping makes co-resident blocks (round-robin XCD dispatch -> consecutive
// blockIdx on one CU) share the SAME slice -> waves 2..N hit K$/L2.
// 2048 blocks = 8/CU restores TLP. cand = u16 global idx (2 MB, ws-safe);
// combine recomputes the 16 candidate dists bit-identically.
__global__ __launch_bounds__(256, 4) void vq_main(const float* __restrict__ x,
                                                  const float* __restrict__ emb,
                                                  const float* __restrict__ enorm,
                                                  unsigned short* __restrict__ cand) {
    const int tid = threadIdx.x;
    const int kq  = blockIdx.x >> 7;      // kq-major: 128 consecutive blocks share kq
    const int gb  = blockIdx.x & 127;     // row group (512 rows)
    const int n0  = gb * ROWS2 + tid;
    const int n1  = n0 + 256;
    const int kbase0 = kq * KPER;

    // two rows of x into registers
    float4 xa[16], xb[16];
    const float4* xp0 = (const float4*)(x + (size_t)n0 * D);
    const float4* xp1 = (const float4*)(x + (size_t)n1 * D);
    #pragma unroll
    for (int i = 0; i < 16; ++i) { xa[i] = xp0[i]; xb[i] = xp1[i]; }

    float xn0 = 0.f, xn1 = 0.f;
    #pragma unroll
    for (int i = 0; i < 16; ++i) {
        float4 a = xa[i], b = xb[i];
        xn0 += a.x * a.x + a.y * a.y + a.z * a.z + a.w * a.w;
        xn1 += b.x * b.x + b.y * b.y + b.z * b.z + b.w * b.w;
    }

    float best0 = 3.4e38f, best1 = 3.4e38f;
    int   bidx0 = kbase0,  bidx1 = kbase0;

    const float4* ebase = (const float4*)(emb + (size_t)kbase0 * D);
    const float*  enb   = enorm + kbase0;

    #pragma unroll 2
    for (int kk = 0; kk < KPER; ++kk) {
        const float4* e4 = ebase + kk * (D / 4);   // uniform address -> s_load
        float p0 = 0.f, p1 = 0.f, p2 = 0.f, p3 = 0.f;
        float q0 = 0.f, q1 = 0.f, q2 = 0.f, q3 = 0.f;
        #pragma unroll
        for (int i = 0; i < 4; ++i) {
            float4 ea = e4[i * 4 + 0], eb = e4[i * 4 + 1];
            float4 ec = e4[i * 4 + 2], ed = e4[i * 4 + 3];
            float4 va = xa[i * 4 + 0], vb = xa[i * 4 + 1];
            float4 vc = xa[i * 4 + 2], vd = xa[i * 4 + 3];
            p0 = fmaf(va.w, ea.w, fmaf(va.z, ea.z, fmaf(va.y, ea.y, fmaf(va.x, ea.x, p0))));
            p1 = fmaf(vb.w, eb.w, fmaf(vb.z, eb.z, fmaf(vb.y, eb.y, fmaf(vb.x, eb.x, p1))));
            p2 = fmaf(vc.w, ec.w, fmaf(vc.z, ec.z, fmaf(vc.y, ec.y, fmaf(vc.x, ec.x, p2))));
            p3 = fmaf(vd.w, ed.w, fmaf(vd.z, ed.z, fmaf(vd.y, ed.y, fmaf(vd.x, ed.x, p3))));
            float4 wa = xb[i * 4 + 0], wb = xb[i * 4 + 1];
            float4 wc = xb[i * 4 + 2], wd = xb[i * 4 + 3];
            q0 = fmaf(wa.w, ea.w, fmaf(wa.z, ea.z, fmaf(wa.y, ea.y, fmaf(wa.x, ea.x, q0))));
            q1 = fmaf(wb.w, eb.w, fmaf(wb.z, eb.z, fmaf(wb.y, eb.y, fmaf(wb.x, eb.x, q1))));
            q2 = fmaf(wc.w, ec.w, fmaf(wc.z, ec.z, fmaf(wc.y, ec.y, fmaf(wc.x, ec.x, q2))));
            q3 = fmaf(wd.w, ed.w, fmaf(wd.z, ed.z, fmaf(wd.y, ed.y, fmaf(wd.x, ed.x, q3))));
        }
        float en   = enb[kk];
        float dot0 = (p0 + p1) + (p2 + p3);
        float dot1 = (q0 + q1) + (q2 + q3);
        float dist0 = fmaf(-2.f, dot0, xn0 + en);
        float dist1 = fmaf(-2.f, dot1, xn1 + en);
        if (dist0 < best0) { best0 = dist0; bidx0 = kbase0 + kk; }  // strict <
        if (dist1 < best1) { best1 = dist1; bidx1 = kbase0 + kk; }
    }

    cand[(size_t)kq * NROWS + n0] = (unsigned short)bidx0;
    cand[(size_t)kq * NROWS + n1] = (unsigned short)bidx1;
}

// ------------------------------------------- combine (exact re-eval) -------
// Recomputes the KSPLIT candidate distances with BIT-IDENTICAL arithmetic
// (same fmaf chains, same xnorm/enorm/dist forms as vq_main) and scans
// splits in ascending-k order with strict < -> exact argmin semantics.
__global__ __launch_bounds__(256) void vq_combine(const float* __restrict__ x,
                                                  const float* __restrict__ emb,
                                                  const float* __restrict__ enorm,
                                                  const unsigned short* __restrict__ cand,
                                                  float* __restrict__ out,
                                                  float* __restrict__ partial) {
    __shared__ float lds_red[256];

    const int tid = threadIdx.x;
    const int n   = blockIdx.x * 256 + tid;

    // x row into registers
    float4 xr[16];
    const float4* xp = (const float4*)(x + (size_t)n * D);
    #pragma unroll
    for (int i = 0; i < 16; ++i) xr[i] = xp[i];

    float xnorm = 0.f;
    #pragma unroll
    for (int i = 0; i < 16; ++i) {
        float4 v = xr[i];
        xnorm += v.x * v.x + v.y * v.y + v.z * v.z + v.w * v.w;
    }

    float best = 3.4e38f;
    int   bi   = 0;

    for (int s = 0; s < KSPLIT; ++s) {
        int k = cand[(size_t)s * NROWS + n];           // per-lane gather
        const float4* e4 = (const float4*)(emb + (size_t)k * D);
        float d0 = 0.f, d1 = 0.f, d2 = 0.f, d3 = 0.f;
        #pragma unroll
        for (int i = 0; i < 4; ++i) {
            float4 ea = e4[i * 4 + 0], eb = e4[i * 4 + 1];
            float4 ec = e4[i * 4 + 2], ed = e4[i * 4 + 3];
            float4 va = xr[i * 4 + 0], vb = xr[i * 4 + 1];
            float4 vc = xr[i * 4 + 2], vd = xr[i * 4 + 3];
            d0 = fmaf(va.w, ea.w, fmaf(va.z, ea.z, fmaf(va.y, ea.y, fmaf(va.x, ea.x, d0))));
            d1 = fmaf(vb.w, eb.w, fmaf(vb.z, eb.z, fmaf(vb.y, eb.y, fmaf(vb.x, eb.x, d1))));
            d2 = fmaf(vc.w, ec.w, fmaf(vc.z, ec.z, fmaf(vc.y, ec.y, fmaf(vc.x, ec.x, d2))));
            d3 = fmaf(vd.w, ed.w, fmaf(vd.z, ed.z, fmaf(vd.y, ed.y, fmaf(vd.x, ed.x, d3))));
        }
        float dot  = (d0 + d1) + (d2 + d3);
        float dist = fmaf(-2.f, dot, xnorm + enorm[k]);
        if (dist < best) { best = dist; bi = k; }      // ascending k; strict <
    }

    // gather chosen row, write output, accumulate squared error
    const float4* q4 = (const float4*)(emb + (size_t)bi * D);
    float4* o4 = (float4*)(out + (size_t)n * D);
    float err = 0.f;
    #pragma unroll
    for (int i = 0; i < 16; ++i) {
        float4 q = q4[i];
        float4 v = xr[i];
        float ax = q.x - v.x, ay = q.y - v.y, az = q.z - v.z, aw = q.w - v.w;
        err += ax * ax + ay * ay + az * az + aw * aw;
        o4[i] = q;
    }

    // deterministic block reduction of err
    __syncthreads();
    lds_red[tid] = err;
    __syncthreads();
    for (int s = 128; s > 0; s >>= 1) {
        if (tid < s) lds_red[tid] += lds_red[tid + s];
        __syncthreads();
    }
    if (tid == 0) partial[blockIdx.x] = lds_red[0];
}

// ------------------------------------------------------------- finalize ----
__global__ __launch_bounds__(256) void vq_finish(const float* __restrict__ partial,
                                                 float* __restrict__ loss_out) {
    __shared__ float lds[256];
    int tid = threadIdx.x;
    lds[tid] = partial[tid];
    __syncthreads();
    for (int s = 128; s > 0; s >>= 1) {
        if (tid < s) lds[tid] += lds[tid + s];
        __syncthreads();
    }
    // loss = codebook + BETA*commitment = (1+BETA) * mean((q-x)^2)
    if (tid == 0) loss_out[0] = (1.0f + BETA) * lds[0] / (float)(NROWS * D);
}

// ---------------------------------------------------------------- launch ---
extern "C" void kernel_launch(void* const* d_in, const int* in_sizes, int n_in,
                              void* d_out, int out_size, void* d_ws, size_t ws_size,
                              hipStream_t stream) {
    const float* x   = (const float*)d_in[0];
    const float* emb = (const float*)d_in[1];
    float* out = (float*)d_out;

    float* enorm = (float*)d_ws;                              // K floats
    float* partial = enorm + K;                               // 256 floats
    unsigned short* cand =
        (unsigned short*)((char*)d_ws + 8192);                // KSPLIT*NROWS u16 = 2 MB

    vq_enorm<<<K / 256, 256, 0, stream>>>(emb, enorm);
    vq_main<<<(NROWS / ROWS2) * KSPLIT, 256, 0, stream>>>(x, emb, enorm, cand);
    vq_combine<<<NROWS / 256, 256, 0, stream>>>(x, emb, enorm, cand, out, partial);
    vq_finish<<<1, 256, 0, stream>>>(partial, out + (size_t)NROWS * D);
}

// Round 10
// 170.164 us; speedup vs baseline: 3.5457x; 3.5457x over previous
//
#include <hip/hip_runtime.h>
#include <math.h>

#define NROWS  65536   // 16*64*64 rows
#define D      64
#define K      1024
#define NCT    8       // code tiles (K / BC)
#define BR     128     // rows per block tile
#define BC     128     // codes per block tile
#define TM     8       // rows per thread (row = 16*i + ty)
#define TN     8       // codes per thread (code = 16*c + tx)
#define BETA   0.25f

// ---------------------------------------------------------------- enorm ----
__global__ __launch_bounds__(256) void vq_enorm(const float* __restrict__ emb,
                                                float* __restrict__ enorm) {
    int k = blockIdx.x * 256 + threadIdx.x;
    if (k >= K) return;
    const float4* e4 = (const float4*)(emb + (size_t)k * D);
    float s = 0.f;
    #pragma unroll
    for (int i = 0; i < 16; ++i) {
        float4 e = e4[i];
        s += e.x * e.x + e.y * e.y + e.z * e.z + e.w * e.w;
    }
    enorm[k] = s;
}

// ---------------------------------------------------------------- xnorm ----
// EXACT same summation order as the proven-passing kernels' xnorm.
__global__ __launch_bounds__(256) void vq_xnorm(const float* __restrict__ x,
                                                float* __restrict__ xn) {
    int n = blockIdx.x * 256 + threadIdx.x;
    const float4* xp = (const float4*)(x + (size_t)n * D);
    float s = 0.f;
    #pragma unroll
    for (int i = 0; i < 16; ++i) {
        float4 v = xp[i];
        s += v.x * v.x + v.y * v.y + v.z * v.z + v.w * v.w;
    }
    xn[n] = s;
}

// ----------------------------------------------------------------- main ----
// Register-tiled distance GEMM. R9 fixes vs R8's failed attempt:
// (1) rank by FULL-form dist fmaf(-2,acc,xn+en): magnitude ~64 quantizes
//     near-ties to the same f32 cell exactly like the np reference; u64
//     (dist,idx) min then tie-breaks to lowest index = argmin semantics.
//     (R8 ranked by en-2dot, magnitude ~0.2: it RESOLVED ties the reference
//     rounds into equality -> wrong picks, absmax 0.085.)
// (2) all-b128 LDS with pure-XOR swizzle slot(r,k4)=r*8+(k4^(r&7)) and
//     lane-mapped rows/codes (16*i+ty, 16*c+tx): x-reads broadcast
//     conflict-free, e-reads 2-way (free), staging writes uniform 8/quad
//     (= return-BW floor). 16 b128/wave-k4 ~ 128 cyc LDS vs 128 cyc VALU.
__global__ __launch_bounds__(256, 4) void vq_main(const float* __restrict__ x,
                                                  const float* __restrict__ emb,
                                                  const float* __restrict__ enorm,
                                                  const float* __restrict__ xn,
                                                  unsigned short* __restrict__ cand) {
    __shared__ float4 xS[BR * 8];              // 16 KB, slot = r*8 + (k4 ^ (r&7))
    __shared__ char   ebuf[BR * 17 * 8];       // 17.4 KB: eS (16 KB) / red overlap
    __shared__ float  enl[BC];                 // 0.5 KB
    __shared__ float  xnl[BR];                 // 0.5 KB
    float4* eS = (float4*)ebuf;
    unsigned long long* red = (unsigned long long*)ebuf;   // [row][17] padded

    const int tid = threadIdx.x;
    const int tx  = tid & 15;
    const int ty  = tid >> 4;
    const int rb  = (int)(blockIdx.x >> 3) * BR;
    const int ct  = (int)(blockIdx.x & 7);
    const int cb  = ct * BC;

    if (tid < BC) enl[tid] = enorm[cb + tid];
    if (tid < BR) xnl[tid] = xn[rb + tid];

    float acc[TM][TN];
    #pragma unroll
    for (int i = 0; i < TM; ++i)
        #pragma unroll
        for (int c = 0; c < TN; ++c) acc[i][c] = 0.f;

    const float4* x4 = (const float4*)x;
    const float4* e4 = (const float4*)emb;

    for (int s = 0; s < 2; ++s) {              // two 32-dim halves
        __syncthreads();
        // stage 128 rows x 8 float4 of x and e into swizzled slots.
        // coalesced global loads; LDS writes spread 8 lanes/bank-quad.
        #pragma unroll
        for (int p = 0; p < 4; ++p) {
            int idx  = p * 256 + tid;          // 0..1023
            int r    = idx >> 3;
            int k4   = idx & 7;
            int slot = r * 8 + (k4 ^ (r & 7));
            xS[slot] = x4[(size_t)(rb + r) * 16 + s * 8 + k4];
            eS[slot] = e4[(size_t)(cb + r) * 16 + s * 8 + k4];
        }
        __syncthreads();

        #pragma unroll 2
        for (int k4 = 0; k4 < 8; ++k4) {
            float4 ev[TN];
            #pragma unroll
            for (int c = 0; c < TN; ++c)       // 8x b128, 2-way (free)
                ev[c] = eS[(16 * c + tx) * 8 + (k4 ^ (tx & 7))];
            #pragma unroll
            for (int i = 0; i < TM; ++i) {     // 8x b128, broadcast, no conflict
                float4 xv = xS[(16 * i + ty) * 8 + (k4 ^ (ty & 7))];
                #pragma unroll
                for (int c = 0; c < TN; ++c) { // k-sequential chain per (i,c)
                    acc[i][c] = fmaf(xv.x, ev[c].x, acc[i][c]);
                    acc[i][c] = fmaf(xv.y, ev[c].y, acc[i][c]);
                    acc[i][c] = fmaf(xv.z, ev[c].z, acc[i][c]);
                    acc[i][c] = fmaf(xv.w, ev[c].w, acc[i][c]);
                }
            }
        }
    }

    // full-form in-tile argmin, packed u64 (orderable dist, idx)
    float xnr[TM];
    #pragma unroll
    for (int i = 0; i < TM; ++i) xnr[i] = xnl[16 * i + ty];

    unsigned long long best[TM];
    #pragma unroll
    for (int i = 0; i < TM; ++i) best[i] = ~0ull;
    #pragma unroll
    for (int c = 0; c < TN; ++c) {
        int   cl = 16 * c + tx;
        float en = enl[cl];
        #pragma unroll
        for (int i = 0; i < TM; ++i) {
            float d = fmaf(-2.f, acc[i][c], xnr[i] + en);   // same final op as R1
            unsigned int b = __float_as_uint(d);
            unsigned int u = (b & 0x80000000u) ? ~b : (b | 0x80000000u);
            unsigned long long pk = ((unsigned long long)u << 32)
                                  | (unsigned int)(cb + cl);
            if (pk < best[i]) best[i] = pk;    // ties -> lowest idx, = argmin
        }
    }

    __syncthreads();                           // eS reads all done (red overlaps)
    #pragma unroll
    for (int i = 0; i < TM; ++i) red[(16 * i + ty) * 17 + tx] = best[i];
    __syncthreads();

    if (tid < BR) {                            // one thread per row
        unsigned long long m = red[tid * 17 + 0];
        #pragma unroll
        for (int j = 1; j < 16; ++j) {
            unsigned long long c = red[tid * 17 + j];
            if (c < m) m = c;
        }
        cand[(size_t)ct * NROWS + rb + tid] = (unsigned short)(m & 0xFFFFu);
    }
}

// ------------------------------------------- combine (exact re-eval) -------
// Verbatim the R8-bench-PASSING combine: recomputes the NCT candidate dists
// with the proven 4-chain fmaf arithmetic; tiles scanned in ascending-k
// order with strict < -> exact argmin semantics.
__global__ __launch_bounds__(256) void vq_combine(const float* __restrict__ x,
                                                  const float* __restrict__ emb,
                                                  const float* __restrict__ enorm,
                                                  const unsigned short* __restrict__ cand,
                                                  float* __restrict__ out,
                                                  float* __restrict__ partial) {
    __shared__ float lds_red[256];

    const int tid = threadIdx.x;
    const int n   = blockIdx.x * 256 + tid;

    float4 xr[16];
    const float4* xp = (const float4*)(x + (size_t)n * D);
    #pragma unroll
    for (int i = 0; i < 16; ++i) xr[i] = xp[i];

    float xnorm = 0.f;
    #pragma unroll
    for (int i = 0; i < 16; ++i) {
        float4 v = xr[i];
        xnorm += v.x * v.x + v.y * v.y + v.z * v.z + v.w * v.w;
    }

    float best = 3.4e38f;
    int   bi   = 0;

    for (int s = 0; s < NCT; ++s) {
        int k = cand[(size_t)s * NROWS + n];           // per-lane gather
        const float4* e4 = (const float4*)(emb + (size_t)k * D);
        float d0 = 0.f, d1 = 0.f, d2 = 0.f, d3 = 0.f;
        #pragma unroll
        for (int i = 0; i < 4; ++i) {
            float4 ea = e4[i * 4 + 0], eb = e4[i * 4 + 1];
            float4 ec = e4[i * 4 + 2], ed = e4[i * 4 + 3];
            float4 va = xr[i * 4 + 0], vb = xr[i * 4 + 1];
            float4 vc = xr[i * 4 + 2], vd = xr[i * 4 + 3];
            d0 = fmaf(va.w, ea.w, fmaf(va.z, ea.z, fmaf(va.y, ea.y, fmaf(va.x, ea.x, d0))));
            d1 = fmaf(vb.w, eb.w, fmaf(vb.z, eb.z, fmaf(vb.y, eb.y, fmaf(vb.x, eb.x, d1))));
            d2 = fmaf(vc.w, ec.w, fmaf(vc.z, ec.z, fmaf(vc.y, ec.y, fmaf(vc.x, ec.x, d2))));
            d3 = fmaf(vd.w, ed.w, fmaf(vd.z, ed.z, fmaf(vd.y, ed.y, fmaf(vd.x, ed.x, d3))));
        }
        float dot  = (d0 + d1) + (d2 + d3);
        float dist = fmaf(-2.f, dot, xnorm + enorm[k]);
        if (dist < best) { best = dist; bi = k; }      // ascending k; strict <
    }

    // gather chosen row, write output, accumulate squared error
    const float4* q4 = (const float4*)(emb + (size_t)bi * D);
    float4* o4 = (float4*)(out + (size_t)n * D);
    float err = 0.f;
    #pragma unroll
    for (int i = 0; i < 16; ++i) {
        float4 q = q4[i];
        float4 v = xr[i];
        float ax = q.x - v.x, ay = q.y - v.y, az = q.z - v.z, aw = q.w - v.w;
        err += ax * ax + ay * ay + az * az + aw * aw;
        o4[i] = q;
    }

    __syncthreads();
    lds_red[tid] = err;
    __syncthreads();
    for (int s = 128; s > 0; s >>= 1) {
        if (tid < s) lds_red[tid] += lds_red[tid + s];
        __syncthreads();
    }
    if (tid == 0) partial[blockIdx.x] = lds_red[0];
}

// ------------------------------------------------------------- finalize ----
__global__ __launch_bounds__(256) void vq_finish(const float* __restrict__ partial,
                                                 float* __restrict__ loss_out) {
    __shared__ float lds[256];
    int tid = threadIdx.x;
    lds[tid] = partial[tid];
    __syncthreads();
    for (int s = 128; s > 0; s >>= 1) {
        if (tid < s) lds[tid] += lds[tid + s];
        __syncthreads();
    }
    // loss = codebook + BETA*commitment = (1+BETA) * mean((q-x)^2)
    if (tid == 0) loss_out[0] = (1.0f + BETA) * lds[0] / (float)(NROWS * D);
}

// ---------------------------------------------------------------- launch ---
extern "C" void kernel_launch(void* const* d_in, const int* in_sizes, int n_in,
                              void* d_out, int out_size, void* d_ws, size_t ws_size,
                              hipStream_t stream) {
    const float* x   = (const float*)d_in[0];
    const float* emb = (const float*)d_in[1];
    float* out = (float*)d_out;

    float* enorm   = (float*)d_ws;                         // K floats (4 KB)
    float* partial = enorm + K;                            // 256 floats
    float* xnbuf   = (float*)((char*)d_ws + 8192);         // NROWS floats (256 KB)
    unsigned short* cand =
        (unsigned short*)((char*)d_ws + 8192 + NROWS * 4); // NCT*NROWS u16 (1 MB)

    vq_enorm<<<K / 256, 256, 0, stream>>>(emb, enorm);
    vq_xnorm<<<NROWS / 256, 256, 0, stream>>>(x, xnbuf);
    vq_main<<<(NROWS / BR) * NCT, 256, 0, stream>>>(x, emb, enorm, xnbuf, cand);
    vq_combine<<<NROWS / 256, 256, 0, stream>>>(x, emb, enorm, cand, out, partial);
    vq_finish<<<1, 256, 0, stream>>>(partial, out + (size_t)NROWS * D);
}

// Round 11
// 163.798 us; speedup vs baseline: 3.6836x; 1.0389x over previous
//
#include <hip/hip_runtime.h>
#include <math.h>

#define NROWS  65536   // 16*64*64 rows
#define D      64
#define K      1024
#define NCT    8       // code tiles (K / BC)
#define BR     128     // rows per block tile
#define BC     128     // codes per block tile
#define TM     8       // rows per thread (row = 16*i + ty)
#define TN     8       // codes per thread (code = 16*c + tx)
#define BETA   0.25f

// ---------------------------------------------------------------- enorm ----
__global__ __launch_bounds__(256) void vq_enorm(const float* __restrict__ emb,
                                                float* __restrict__ enorm) {
    int k = blockIdx.x * 256 + threadIdx.x;
    if (k >= K) return;
    const float4* e4 = (const float4*)(emb + (size_t)k * D);
    float s = 0.f;
    #pragma unroll
    for (int i = 0; i < 16; ++i) {
        float4 e = e4[i];
        s += e.x * e.x + e.y * e.y + e.z * e.z + e.w * e.w;
    }
    enorm[k] = s;
}

// ---------------------------------------------------------------- xnorm ----
// EXACT same summation order as the proven-passing kernels' xnorm.
__global__ __launch_bounds__(256) void vq_xnorm(const float* __restrict__ x,
                                                float* __restrict__ xn) {
    int n = blockIdx.x * 256 + threadIdx.x;
    const float4* xp = (const float4*)(x + (size_t)n * D);
    float s = 0.f;
    #pragma unroll
    for (int i = 0; i < 16; ++i) {
        float4 v = xp[i];
        s += v.x * v.x + v.y * v.y + v.z * v.z + v.w * v.w;
    }
    xn[n] = s;
}

// ----------------------------------------------------------------- main ----
// Register-tiled distance GEMM (R10 PASSED with this exact arithmetic).
// R11 change: __launch_bounds__(256, 2). R10's (256,4) made the allocator
// target the 64-VGPR bin (8 waves/EU) even though LDS (34.8KB -> 4 blk/CU)
// caps us at 4 waves/EU anyway -- it spilled ~20KB/block to scratch
// (WRITE_SIZE 83MB, VALU-issue 99us vs 55us FMA floor). Cap 256 lets the
// ~120-reg live set (acc 64 + frags + addr) sit in registers; <=128 keeps
// the same 4 waves/EU occupancy LDS already dictates.
__global__ __launch_bounds__(256, 2) void vq_main(const float* __restrict__ x,
                                                  const float* __restrict__ emb,
                                                  const float* __restrict__ enorm,
                                                  const float* __restrict__ xn,
                                                  unsigned short* __restrict__ cand) {
    __shared__ float4 xS[BR * 8];              // 16 KB, slot = r*8 + (k4 ^ (r&7))
    __shared__ char   ebuf[BR * 17 * 8];       // 17.4 KB: eS (16 KB) / red overlap
    __shared__ float  enl[BC];                 // 0.5 KB
    __shared__ float  xnl[BR];                 // 0.5 KB
    float4* eS = (float4*)ebuf;
    unsigned long long* red = (unsigned long long*)ebuf;   // [row][17] padded

    const int tid = threadIdx.x;
    const int tx  = tid & 15;
    const int ty  = tid >> 4;
    const int rb  = (int)(blockIdx.x >> 3) * BR;
    const int ct  = (int)(blockIdx.x & 7);
    const int cb  = ct * BC;

    if (tid < BC) enl[tid] = enorm[cb + tid];
    if (tid < BR) xnl[tid] = xn[rb + tid];

    float acc[TM][TN];
    #pragma unroll
    for (int i = 0; i < TM; ++i)
        #pragma unroll
        for (int c = 0; c < TN; ++c) acc[i][c] = 0.f;

    const float4* x4 = (const float4*)x;
    const float4* e4 = (const float4*)emb;

    for (int s = 0; s < 2; ++s) {              // two 32-dim halves
        __syncthreads();
        // stage 128 rows x 8 float4 of x and e into swizzled slots.
        #pragma unroll
        for (int p = 0; p < 4; ++p) {
            int idx  = p * 256 + tid;          // 0..1023
            int r    = idx >> 3;
            int k4   = idx & 7;
            int slot = r * 8 + (k4 ^ (r & 7));
            xS[slot] = x4[(size_t)(rb + r) * 16 + s * 8 + k4];
            eS[slot] = e4[(size_t)(cb + r) * 16 + s * 8 + k4];
        }
        __syncthreads();

        #pragma unroll 2
        for (int k4 = 0; k4 < 8; ++k4) {
            float4 ev[TN];
            #pragma unroll
            for (int c = 0; c < TN; ++c)       // 8x b128, 2-way (free)
                ev[c] = eS[(16 * c + tx) * 8 + (k4 ^ (tx & 7))];
            #pragma unroll
            for (int i = 0; i < TM; ++i) {     // 8x b128, broadcast, no conflict
                float4 xv = xS[(16 * i + ty) * 8 + (k4 ^ (ty & 7))];
                #pragma unroll
                for (int c = 0; c < TN; ++c) { // k-sequential chain per (i,c)
                    acc[i][c] = fmaf(xv.x, ev[c].x, acc[i][c]);
                    acc[i][c] = fmaf(xv.y, ev[c].y, acc[i][c]);
                    acc[i][c] = fmaf(xv.z, ev[c].z, acc[i][c]);
                    acc[i][c] = fmaf(xv.w, ev[c].w, acc[i][c]);
                }
            }
        }
    }

    // full-form in-tile argmin, packed u64 (orderable dist, idx)
    float xnr[TM];
    #pragma unroll
    for (int i = 0; i < TM; ++i) xnr[i] = xnl[16 * i + ty];

    unsigned long long best[TM];
    #pragma unroll
    for (int i = 0; i < TM; ++i) best[i] = ~0ull;
    #pragma unroll
    for (int c = 0; c < TN; ++c) {
        int   cl = 16 * c + tx;
        float en = enl[cl];
        #pragma unroll
        for (int i = 0; i < TM; ++i) {
            float d = fmaf(-2.f, acc[i][c], xnr[i] + en);   // same final op as R1
            unsigned int b = __float_as_uint(d);
            unsigned int u = (b & 0x80000000u) ? ~b : (b | 0x80000000u);
            unsigned long long pk = ((unsigned long long)u << 32)
                                  | (unsigned int)(cb + cl);
            if (pk < best[i]) best[i] = pk;    // ties -> lowest idx, = argmin
        }
    }

    __syncthreads();                           // eS reads all done (red overlaps)
    #pragma unroll
    for (int i = 0; i < TM; ++i) red[(16 * i + ty) * 17 + tx] = best[i];
    __syncthreads();

    if (tid < BR) {                            // one thread per row
        unsigned long long m = red[tid * 17 + 0];
        #pragma unroll
        for (int j = 1; j < 16; ++j) {
            unsigned long long c = red[tid * 17 + j];
            if (c < m) m = c;
        }
        cand[(size_t)ct * NROWS + rb + tid] = (unsigned short)(m & 0xFFFFu);
    }
}

// ------------------------------------------- combine (exact re-eval) -------
// Verbatim the bench-PASSING combine: recomputes the NCT candidate dists
// with the proven 4-chain fmaf arithmetic; tiles scanned in ascending-k
// order with strict < -> exact argmin semantics.
__global__ __launch_bounds__(256) void vq_combine(const float* __restrict__ x,
                                                  const float* __restrict__ emb,
                                                  const float* __restrict__ enorm,
                                                  const unsigned short* __restrict__ cand,
                                                  float* __restrict__ out,
                                                  float* __restrict__ partial) {
    __shared__ float lds_red[256];

    const int tid = threadIdx.x;
    const int n   = blockIdx.x * 256 + tid;

    float4 xr[16];
    const float4* xp = (const float4*)(x + (size_t)n * D);
    #pragma unroll
    for (int i = 0; i < 16; ++i) xr[i] = xp[i];

    float xnorm = 0.f;
    #pragma unroll
    for (int i = 0; i < 16; ++i) {
        float4 v = xr[i];
        xnorm += v.x * v.x + v.y * v.y + v.z * v.z + v.w * v.w;
    }

    float best = 3.4e38f;
    int   bi   = 0;

    for (int s = 0; s < NCT; ++s) {
        int k = cand[(size_t)s * NROWS + n];           // per-lane gather
        const float4* e4 = (const float4*)(emb + (size_t)k * D);
        float d0 = 0.f, d1 = 0.f, d2 = 0.f, d3 = 0.f;
        #pragma unroll
        for (int i = 0; i < 4; ++i) {
            float4 ea = e4[i * 4 + 0], eb = e4[i * 4 + 1];
            float4 ec = e4[i * 4 + 2], ed = e4[i * 4 + 3];
            float4 va = xr[i * 4 + 0], vb = xr[i * 4 + 1];
            float4 vc = xr[i * 4 + 2], vd = xr[i * 4 + 3];
            d0 = fmaf(va.w, ea.w, fmaf(va.z, ea.z, fmaf(va.y, ea.y, fmaf(va.x, ea.x, d0))));
            d1 = fmaf(vb.w, eb.w, fmaf(vb.z, eb.z, fmaf(vb.y, eb.y, fmaf(vb.x, eb.x, d1))));
            d2 = fmaf(vc.w, ec.w, fmaf(vc.z, ec.z, fmaf(vc.y, ec.y, fmaf(vc.x, ec.x, d2))));
            d3 = fmaf(vd.w, ed.w, fmaf(vd.z, ed.z, fmaf(vd.y, ed.y, fmaf(vd.x, ed.x, d3))));
        }
        float dot  = (d0 + d1) + (d2 + d3);
        float dist = fmaf(-2.f, dot, xnorm + enorm[k]);
        if (dist < best) { best = dist; bi = k; }      // ascending k; strict <
    }

    // gather chosen row, write output, accumulate squared error
    const float4* q4 = (const float4*)(emb + (size_t)bi * D);
    float4* o4 = (float4*)(out + (size_t)n * D);
    float err = 0.f;
    #pragma unroll
    for (int i = 0; i < 16; ++i) {
        float4 q = q4[i];
        float4 v = xr[i];
        float ax = q.x - v.x, ay = q.y - v.y, az = q.z - v.z, aw = q.w - v.w;
        err += ax * ax + ay * ay + az * az + aw * aw;
        o4[i] = q;
    }

    __syncthreads();
    lds_red[tid] = err;
    __syncthreads();
    for (int s = 128; s > 0; s >>= 1) {
        if (tid < s) lds_red[tid] += lds_red[tid + s];
        __syncthreads();
    }
    if (tid == 0) partial[blockIdx.x] = lds_red[0];
}

// ------------------------------------------------------------- finalize ----
__global__ __launch_bounds__(256) void vq_finish(const float* __restrict__ partial,
                                                 float* __restrict__ loss_out) {
    __shared__ float lds[256];
    int tid = threadIdx.x;
    lds[tid] = partial[tid];
    __syncthreads();
    for (int s = 128; s > 0; s >>= 1) {
        if (tid < s) lds[tid] += lds[tid + s];
        __syncthreads();
    }
    // loss = codebook + BETA*commitment = (1+BETA) * mean((q-x)^2)
    if (tid == 0) loss_out[0] = (1.0f + BETA) * lds[0] / (float)(NROWS * D);
}

// ---------------------------------------------------------------- launch ---
extern "C" void kernel_launch(void* const* d_in, const int* in_sizes, int n_in,
                              void* d_out, int out_size, void* d_ws, size_t ws_size,
                              hipStream_t stream) {
    const float* x   = (const float*)d_in[0];
    const float* emb = (const float*)d_in[1];
    float* out = (float*)d_out;

    float* enorm   = (float*)d_ws;                         // K floats (4 KB)
    float* partial = enorm + K;                            // 256 floats
    float* xnbuf   = (float*)((char*)d_ws + 8192);         // NROWS floats (256 KB)
    unsigned short* cand =
        (unsigned short*)((char*)d_ws + 8192 + NROWS * 4); // NCT*NROWS u16 (1 MB)

    vq_enorm<<<K / 256, 256, 0, stream>>>(emb, enorm);
    vq_xnorm<<<NROWS / 256, 256, 0, stream>>>(x, xnbuf);
    vq_main<<<(NROWS / BR) * NCT, 256, 0, stream>>>(x, emb, enorm, xnbuf, cand);
    vq_combine<<<NROWS / 256, 256, 0, stream>>>(x, emb, enorm, cand, out, partial);
    vq_finish<<<1, 256, 0, stream>>>(partial, out + (size_t)NROWS * D);
}